// Round 18
// baseline (265.035 us; speedup 1.0000x reference)
//
#include <hip/hip_runtime.h>
#include <math.h>

// ---------------------------------------------------------------------------
// LinearAttention: B=16, DIM=256, H=W=64 (n=4096), HEADS=8, DH=64, INNER=512
// Round 18: ctx 256->512 threads/block. r17 showed ctx's stall is NOT data
// residency (XCD swizzle halved FETCH, time flat) but wave-level parallelism:
// 2 waves/SIMD. Same window/LDS (71.7KB, 2 blocks/CU) with 8 waves/block ->
// 4 waves/SIMD. Per-wave tile 32px x 64ch (acc1 halves -> VGPR ~130). GEMM2
// px-contraction split across wpx-pairs; 8 ctx_part slots/bh (merge sums 8).
// dwt/qpv/wout unchanged from round 17 (keep XCD grouping: FETCH halved).
// ---------------------------------------------------------------------------

static constexpr int NPIX = 4096;
typedef long long i64;
typedef __attribute__((ext_vector_type(8))) short s16x8;
typedef __attribute__((ext_vector_type(8))) _Float16 f16x8;
typedef __attribute__((ext_vector_type(4))) float f32x4;

__device__ inline f32x4 MF(s16x8 a, s16x8 b, f32x4 c) {
  return __builtin_amdgcn_mfma_f32_16x16x32_f16(
      __builtin_bit_cast(f16x8, a), __builtin_bit_cast(f16x8, b), c, 0, 0, 0);
}
__device__ inline short f2h(float x) {
  return __builtin_bit_cast(short, (_Float16)x);
}
__device__ inline unsigned pk2(float a, float b) {
  return (unsigned)(unsigned short)f2h(a) | ((unsigned)(unsigned short)f2h(b) << 16);
}

#define LDX 72    // Xs row stride in shorts (64 c + 8 pad, 144B)
#define LDK 136   // kh/vv row stride in shorts (128 px + 8 pad; 17 groups ≡ 1 mod 8)
#define LDQ 72    // qh row stride in shorts (64 + 8 pad, 144B)

// ---------------- K1: depthwise 3x3 + transpose; optional fmapT pass -------
__global__ __launch_bounds__(256) void dwt_kernel(const float* __restrict__ fmap,
                                                  const float* __restrict__ Wdw,
                                                  short* __restrict__ dwT,
                                                  short* __restrict__ fmapT) {
  __shared__ short T[64 * 260];
  const int pxt = blockIdx.x * 256, ct = blockIdx.y * 64, b = blockIdx.z;
  const int t = threadIdx.x;
  const int x0 = pxt >> 6;
  const int yq = t & 15, xq = (t >> 4) & 3, clo = t >> 6;
  const int y0 = yq * 4;
  const int x = x0 + xq;
  #pragma unroll 2
  for (int cc = 0; cc < 16; ++cc) {
    const int cl = cc * 4 + clo;
    const int cg = ct + cl;
    const float* img = fmap + (i64)(b * 256 + cg) * NPIX;
    const float* w = Wdw + cg * 9;
    float a0 = 0.f, a1 = 0.f, a2 = 0.f, a3 = 0.f;
    #pragma unroll
    for (int dx = -1; dx <= 1; ++dx) {
      const int xx = x + dx;
      if ((unsigned)xx < 64u) {
        const float* row = img + xx * 64 + y0;
        const f32x4 v = *(const f32x4*)row;
        const float vm = (y0 > 0)  ? row[-1] : 0.f;
        const float vp = (y0 < 60) ? row[4]  : 0.f;
        const float wm = w[(dx + 1) * 3], wc = w[(dx + 1) * 3 + 1], wp = w[(dx + 1) * 3 + 2];
        a0 = fmaf(wm, vm,   fmaf(wc, v[0], fmaf(wp, v[1], a0)));
        a1 = fmaf(wm, v[0], fmaf(wc, v[1], fmaf(wp, v[2], a1)));
        a2 = fmaf(wm, v[1], fmaf(wc, v[2], fmaf(wp, v[3], a2)));
        a3 = fmaf(wm, v[2], fmaf(wc, v[3], fmaf(wp, vp,   a3)));
      }
    }
    *(uint2*)&T[cl * 260 + xq * 64 + y0] = make_uint2(pk2(a0, a1), pk2(a2, a3));
  }
  __syncthreads();
  {
    short arr[64];
    #pragma unroll
    for (int c = 0; c < 64; ++c) arr[c] = T[c * 260 + t];
    short* dp = dwT + ((i64)b * NPIX + pxt + t) * 256 + ct;
    #pragma unroll
    for (int j = 0; j < 8; ++j)
      *(uint4*)&dp[j * 8] = *(const uint4*)&arr[j * 8];
  }
  if (fmapT) {
    __syncthreads();
    #pragma unroll 4
    for (int cc = 0; cc < 16; ++cc) {
      const int cl = cc * 4 + clo;
      const float* img = fmap + (i64)(b * 256 + ct + cl) * NPIX;
      const f32x4 vc = *(const f32x4*)(img + x * 64 + y0);
      *(uint2*)&T[cl * 260 + xq * 64 + y0] = make_uint2(pk2(vc[0], vc[1]), pk2(vc[2], vc[3]));
    }
    __syncthreads();
    short arr[64];
    #pragma unroll
    for (int c = 0; c < 64; ++c) arr[c] = T[c * 260 + t];
    short* fp = fmapT + ((i64)b * NPIX + pxt + t) * 256 + ct;
    #pragma unroll
    for (int j = 0; j < 8; ++j)
      *(uint4*)&fp[j * 8] = *(const uint4*)&arr[j * 8];
  }
}

// ---------------- K2: weights -> fp16 --------------------------------------
__global__ __launch_bounds__(256) void wprep_kernel(const float* __restrict__ Wq,
                                                    const float* __restrict__ Wpw,
                                                    const float* __restrict__ Wout,
                                                    short* __restrict__ wh) {
  int i = blockIdx.x * 256 + threadIdx.x;
  float v;
  if (i < 131072) v = Wq[i];
  else if (i < 393216) v = Wpw[i - 131072];
  else v = Wout[i - 393216];
  wh[i] = f2h(v);
}

// ---------------- K3: transpose+convert fp32 [c][px] -> fp16 [px][c] -------
// (S=2 fallback path only)
__global__ __launch_bounds__(256) void tcvt_kernel(const float* __restrict__ src,
                                                   short* __restrict__ dst,
                                                   int src_px0, int nsl) {
  __shared__ short T[64 * 260];
  const int pxt = blockIdx.x * 256, ct = blockIdx.y * 64, b = blockIdx.z;
  const int t = threadIdx.x;
  const int pxq = t & 63, cl = t >> 6;
  const float* sp = src + (i64)(b * 256 + ct) * NPIX + src_px0 + pxt;
  #pragma unroll
  for (int cc = 0; cc < 16; ++cc) {
    const int c = cl + cc * 4;
    f32x4 v = *(const f32x4*)&sp[(i64)c * NPIX + pxq * 4];
    *(uint2*)&T[c * 260 + pxq * 4] = make_uint2(pk2(v[0], v[1]), pk2(v[2], v[3]));
  }
  __syncthreads();
  short arr[64];
  #pragma unroll
  for (int c = 0; c < 64; ++c) arr[c] = T[c * 260 + t];
  short* dp = dst + ((i64)b * nsl + pxt + t) * 256 + ct;
  #pragma unroll
  for (int j = 0; j < 8; ++j)
    *(uint4*)&dp[j * 8] = *(const uint4*)&arr[j * 8];
}

// ---------------- K4: fused k/v GEMM + exp + ctx partial -------------------
// 512 blocks x 512 threads (8 waves). Wave (wcv, wpx): GEMM1 tile 32px x 64ch.
// Same LDS as r16/17 (71.7KB -> 2 blocks/CU) but 16 waves/CU = 4/SIMD.
// GEMM2: wave (wcv, eq=wpx&1, ph2=wpx>>1) computes quadrant partial over
// px-half ph2 -> ctx_part slot chunk*2+ph2 (8 slots/bh; merge sums 8).
__global__ __launch_bounds__(512) void ctx_kernel(const short* __restrict__ wh,
                                                  const short* __restrict__ dwT,
                                                  float* __restrict__ ctx_part,
                                                  float* __restrict__ s_part) {
  __shared__ short Xs[2][128 * LDX];
  __shared__ short kh[64 * LDK];
  __shared__ short vv[64 * LDK];
  const int bid = blockIdx.x;
  const int logical = (bid & 7) * 64 + (bid >> 3);   // XCD grouping (r17)
  const int h = logical & 7;
  const int chunk = (logical >> 3) & 3;
  const int b = logical >> 5;
  const int tid = threadIdx.x, lane = tid & 63, w = tid >> 6;   // w 0..7
  const int fr = lane & 15, fg = lane >> 4;
  const int wcv = w & 1;                   // k/v half
  const int wpx = w >> 1;                  // px quarter 0..3
  const int eq = wpx & 1, ph2 = wpx >> 1;  // GEMM2: e-half, px-half
  const int wrow0 = (wcv ? 512 : 0) + h * 64;
  const short* W = wh + 131072 + (i64)wrow0 * 256;
  const short* Xg = dwT + ((i64)b * NPIX + chunk * 1024) * 256;

  f32x4 acc2[2][2];
  #pragma unroll
  for (int m = 0; m < 2; ++m)
    #pragma unroll
    for (int n = 0; n < 2; ++n) acc2[m][n] = (f32x4)0.f;
  float srun[4] = {0.f, 0.f, 0.f, 0.f};

  const int r0 = tid >> 3, scq = tid & 7;  // staging: 64 rows x 8 col-groups, x2
  s16x8 sv[2];
  s16x8 Wr[2][4];                          // single buffer [k2][n]
  auto cload = [&](int g) {
    const int itg = g >> 2, c0g = (g & 3) * 64;
    #pragma unroll
    for (int j = 0; j < 2; ++j)
      sv[j] = *(const s16x8*)&Xg[(i64)(itg * 128 + r0 + j * 64) * 256 + c0g + scq * 8];
  };
  auto cwrite = [&](int bf) {
    #pragma unroll
    for (int j = 0; j < 2; ++j) {
      const int r = r0 + j * 64;
      *(s16x8*)&Xs[bf][r * LDX + ((scq ^ ((r >> 4) & 7)) * 8)] = sv[j];
    }
  };
  auto wload = [&](int g) {
    const int c0g = (g & 3) * 64;
    #pragma unroll
    for (int k2 = 0; k2 < 2; ++k2)
      #pragma unroll
      for (int n = 0; n < 4; ++n)
        Wr[k2][n] = *(const s16x8*)&W[(i64)(n * 16 + fr) * 256 + c0g + k2 * 32 + fg * 8];
  };

  // prologue: Xs[0] <- data0; sv <- data1; Wr <- W0
  cload(0);
  wload(0);
  cwrite(0);
  cload(1);
  __syncthreads();

  for (int it = 0; it < 8; ++it) {
    f32x4 acc1[2][4];
    #pragma unroll
    for (int m = 0; m < 2; ++m)
      #pragma unroll
      for (int n = 0; n < 4; ++n) acc1[m][n] = (f32x4)0.f;

    #pragma unroll
    for (int ks = 0; ks < 4; ++ks) {
      const int g = it * 4 + ks;           // g&1 == ks&1 (it*4 even)
      if (g < 31) cwrite((ks + 1) & 1);    // data loaded a full window ago
      if (g < 30) cload(g + 2);            // refill sv, 2 windows ahead
      const short* Xb = Xs[ks & 1];
      #pragma unroll
      for (int k2 = 0; k2 < 2; ++k2) {
        s16x8 a[2];
        #pragma unroll
        for (int m = 0; m < 2; ++m) {
          const int px = wpx * 32 + m * 16 + fr;
          a[m] = *(const s16x8*)&Xb[px * LDX + (((k2 * 4 + fg) ^ ((px >> 4) & 7)) & 7) * 8];
        }
        #pragma unroll
        for (int m = 0; m < 2; ++m)
          #pragma unroll
          for (int n = 0; n < 4; ++n)
            acc1[m][n] = MF(a[m], Wr[k2][n], acc1[m][n]);
      }
      if (g < 31) wload(g + 1);            // Wr dead after window's MFMAs
      __syncthreads();
    }
    // k-half: exp (no max-sub; values bounded), per-channel running sums
    if (wcv == 0) {
      #pragma unroll
      for (int m = 0; m < 2; ++m)
        #pragma unroll
        for (int n = 0; n < 4; ++n)
          #pragma unroll
          for (int r = 0; r < 4; ++r) {
            float e = __expf(acc1[m][n][r]);
            acc1[m][n][r] = e;
            srun[n] += e;
          }
    }
    // packed writes into [ch][px]; NO XOR (LDK stride rotates banks)
    {
      short* dst = wcv ? vv : kh;
      #pragma unroll
      for (int m = 0; m < 2; ++m)
        #pragma unroll
        for (int n = 0; n < 4; ++n) {
          const int ch = n * 16 + fr;
          const int col = (wpx * 4 + m * 2 + (fg >> 1)) * 8 + (fg & 1) * 4;
          *(uint2*)&dst[ch * LDK + col] =
              make_uint2(pk2(acc1[m][n][0], acc1[m][n][1]),
                         pk2(acc1[m][n][2], acc1[m][n][3]));
        }
    }
    __syncthreads();
    // GEMM2: quadrant (wcv,eq) partial over px-half ph2 (64 px = 2 k2 steps)
    #pragma unroll
    for (int k2 = 0; k2 < 2; ++k2) {
      const int colg = (ph2 * 8 + k2 * 4 + fg) * 8;
      s16x8 a2[2], b2[2];
      #pragma unroll
      for (int m2 = 0; m2 < 2; ++m2)
        a2[m2] = *(const s16x8*)&kh[(wcv * 32 + m2 * 16 + fr) * LDK + colg];
      #pragma unroll
      for (int n2 = 0; n2 < 2; ++n2)
        b2[n2] = *(const s16x8*)&vv[(eq * 32 + n2 * 16 + fr) * LDK + colg];
      #pragma unroll
      for (int m2 = 0; m2 < 2; ++m2)
        #pragma unroll
        for (int n2 = 0; n2 < 2; ++n2)
          acc2[m2][n2] = MF(a2[m2], b2[n2], acc2[m2][n2]);
    }
    // no bottom barrier: next it's window barriers separate GEMM2 reads
    // from the next kh/vv writes.
  }
  __syncthreads();   // last GEMM2 reads done before kh reuse as sredp
  // write ctx partial [d][e]: slot = chunk*2 + ph2
  float* cp = ctx_part + (i64)((b * 8 + h) * 8 + chunk * 2 + ph2) * 4096;
  #pragma unroll
  for (int m2 = 0; m2 < 2; ++m2)
    #pragma unroll
    for (int n2 = 0; n2 < 2; ++n2)
      #pragma unroll
      for (int r = 0; r < 4; ++r) {
        const int d = wcv * 32 + m2 * 16 + fg * 4 + r;
        const int e = eq * 32 + n2 * 16 + fr;
        cp[d * 64 + e] = acc2[m2][n2][r];
      }
  // per-channel sumexp: reduce over fg lanes, stash 4 wpx segments in kh
  float* sredp = (float*)kh;
  if (wcv == 0) {
    #pragma unroll
    for (int n = 0; n < 4; ++n) {
      float s = srun[n];
      s += __shfl_xor(s, 16);
      s += __shfl_xor(s, 32);
      if (fg == 0) sredp[wpx * 64 + n * 16 + fr] = s;
    }
  }
  __syncthreads();
  if (tid < 64)
    s_part[(i64)((b * 8 + h) * 4 + chunk) * 64 + tid] =
        sredp[tid] + sredp[64 + tid] + sredp[128 + tid] + sredp[192 + tid];
}

// ---------------- K5: merge chunk partials -> ctxh fp16 [bh][e][d] ---------
// ctx_part: 8 slots/bh; s_part: 4 slots/bh.
__global__ __launch_bounds__(256) void merge_kernel(const float* __restrict__ part,
                                                    const float* __restrict__ s_part,
                                                    short* __restrict__ ctxh) {
  const int bh = blockIdx.x, t = threadIdx.x;
  const int e = t & 63, db = t >> 6;
  const float* p = part + (i64)bh * 8 * 4096;
  const float* sp = s_part + (i64)bh * 4 * 64;
  #pragma unroll 4
  for (int dd = 0; dd < 16; ++dd) {
    const int d = db * 16 + dd;
    float s = 0.f, c = 0.f;
    #pragma unroll
    for (int k = 0; k < 4; ++k) s += sp[k * 64 + d];
    #pragma unroll
    for (int k = 0; k < 8; ++k) c += p[k * 4096 + d * 64 + e];
    ctxh[(i64)bh * 4096 + e * 64 + d] = f2h(c / s);
  }
}

// ---------------- K6: fused q GEMM + softmax + PV + GELU -> out2 -----------
// 1-D grid, XCD-grouped (r17). Load-early staging + W reg dbuf + hoisted ctxh.
__global__ __launch_bounds__(256) void qpv_kernel(const short* __restrict__ wh,
                                                  const short* __restrict__ fmapT,
                                                  const short* __restrict__ ctxh,
                                                  short* __restrict__ out2,
                                                  int NS, int nPx) {
  __shared__ short Xs[128 * LDX];
  __shared__ short qh[128 * LDQ];
  __shared__ float sden[2][128];
  const int bid = blockIdx.x;
  const int total = nPx * 128;
  const int logical = (bid & 7) * (total >> 3) + (bid >> 3);
  const int h = logical & 7;
  const int rest = logical >> 3;
  const int pxb = rest % nPx;
  const int b = rest / nPx;
  const int i0 = pxb * 128;
  const int tid = threadIdx.x, lane = tid & 63, w = tid >> 6;
  const int fr = lane & 15, fg = lane >> 4;
  const int dh = w & 1, ih = w >> 1;
  const short* W = wh + (i64)(h * 64 + dh * 32) * 256;
  const short* Xg = fmapT + ((i64)b * NS + i0) * 256;

  const i64 cbase = (i64)(b * 8 + h) * 4096;
  s16x8 ca[2][2];                          // [k2][m2]
  #pragma unroll
  for (int k2 = 0; k2 < 2; ++k2)
    #pragma unroll
    for (int m2 = 0; m2 < 2; ++m2)
      ca[k2][m2] = *(const s16x8*)&ctxh[cbase + (i64)(dh * 32 + m2 * 16 + fr) * 64 + k2 * 32 + fg * 8];

  f32x4 acc[2][4];
  #pragma unroll
  for (int m = 0; m < 2; ++m)
    #pragma unroll
    for (int n = 0; n < 4; ++n) acc[m][n] = (f32x4)0.f;

  const int r0 = tid >> 3, scq = tid & 7;
  s16x8 sv[4];
  s16x8 Wr[2][2][2];                       // [buf][k2][m]
  auto qload = [&](int g) {
    #pragma unroll
    for (int j = 0; j < 4; ++j)
      sv[j] = *(const s16x8*)&Xg[(i64)(r0 + j * 32) * 256 + g * 64 + scq * 8];
  };
  auto qwrite = [&]() {
    #pragma unroll
    for (int j = 0; j < 4; ++j) {
      const int r = r0 + j * 32;
      *(s16x8*)&Xs[r * LDX + ((scq ^ ((r >> 4) & 7)) * 8)] = sv[j];
    }
  };
  auto wqload = [&](int g, int bf) {
    #pragma unroll
    for (int k2 = 0; k2 < 2; ++k2)
      #pragma unroll
      for (int m = 0; m < 2; ++m)
        Wr[bf][k2][m] = *(const s16x8*)&W[(i64)(m * 16 + fr) * 256 + g * 64 + k2 * 32 + fg * 8];
  };

  qload(0);
  wqload(0, 0);

  for (int ks = 0; ks < 4; ++ks) {         // BK = 64
    qwrite();                              // drains vmcnt for window-ks loads
    if (ks < 3) {
      qload(ks + 1);
      wqload(ks + 1, (ks + 1) & 1);
    }
    __syncthreads();
    #pragma unroll
    for (int k2 = 0; k2 < 2; ++k2) {
      s16x8 bfr[4];
      #pragma unroll
      for (int n = 0; n < 4; ++n) {
        const int px = ih * 64 + n * 16 + fr;
        bfr[n] = *(const s16x8*)&Xs[px * LDX + (((k2 * 4 + fg) ^ (ih * 4 + n)) & 7) * 8];
      }
      #pragma unroll
      for (int m = 0; m < 2; ++m)
        #pragma unroll
        for (int n = 0; n < 4; ++n)
          acc[m][n] = MF(Wr[ks & 1][k2][m], bfr[n], acc[m][n]);
    }
    __syncthreads();
  }
  // exp + per-pixel denominator across d (2 waves x 32 d)
  #pragma unroll
  for (int n = 0; n < 4; ++n) {
    float s = 0.f;
    #pragma unroll
    for (int m = 0; m < 2; ++m)
      #pragma unroll
      for (int r = 0; r < 4; ++r) {
        float e = __expf(acc[m][n][r]);
        acc[m][n][r] = e;
        s += e;
      }
    s += __shfl_xor(s, 16);
    s += __shfl_xor(s, 32);
    if (fg == 0) sden[dh][ih * 64 + n * 16 + fr] = s;
  }
  __syncthreads();
  if (tid < 128) sden[0][tid] += sden[1][tid];
  __syncthreads();
  // qhat -> LDS [px][d] fp16 (uint2-packed 4-d chunks)
  #pragma unroll
  for (int n = 0; n < 4; ++n) {
    const int il = ih * 64 + n * 16 + fr;
    const float rs = 0.125f / sden[0][il];
    #pragma unroll
    for (int m = 0; m < 2; ++m) {
      const int d0 = dh * 32 + m * 16 + fg * 4;
      *(uint2*)&qh[il * LDQ + d0] =
          make_uint2(pk2(acc[m][n][0] * rs, acc[m][n][1] * rs),
                     pk2(acc[m][n][2] * rs, acc[m][n][3] * rs));
    }
  }
  __syncthreads();
  // PV: out2[e][px] = sum_d ctx[e][d] * qhat[px][d]  (A = hoisted ca)
  f32x4 acc3[2][4];
  #pragma unroll
  for (int m = 0; m < 2; ++m)
    #pragma unroll
    for (int n = 0; n < 4; ++n) acc3[m][n] = (f32x4)0.f;
  #pragma unroll
  for (int k2 = 0; k2 < 2; ++k2) {
    s16x8 b2[4];
    #pragma unroll
    for (int n2 = 0; n2 < 4; ++n2)
      b2[n2] = *(const s16x8*)&qh[(ih * 64 + n2 * 16 + fr) * LDQ + k2 * 32 + fg * 8];
    #pragma unroll
    for (int m2 = 0; m2 < 2; ++m2)
      #pragma unroll
      for (int n2 = 0; n2 < 4; ++n2)
        acc3[m2][n2] = MF(ca[k2][m2], b2[n2], acc3[m2][n2]);
  }
  __syncthreads();   // qh reads done; reuse as transpose buffer
  // GELU + fp16, into qh as [px][e]
  #pragma unroll
  for (int m2 = 0; m2 < 2; ++m2)
    #pragma unroll
    for (int n2 = 0; n2 < 4; ++n2) {
      const int px = ih * 64 + n2 * 16 + fr;
      const int e0 = dh * 32 + m2 * 16 + fg * 4;
      float g[4];
      #pragma unroll
      for (int r = 0; r < 4; ++r) {
        float v = acc3[m2][n2][r];
        g[r] = 0.5f * v * (1.0f + erff(v * 0.70710678118654752f));
      }
      *(uint2*)&qh[px * LDQ + e0] = make_uint2(pk2(g[0], g[1]), pk2(g[2], g[3]));
    }
  __syncthreads();
  // coalesced out2 store: [b][px][512ch]
  {
    const int px = tid >> 1, half = tid & 1;
    short* op = out2 + ((i64)b * NS + i0 + px) * 512 + h * 64 + half * 32;
    #pragma unroll
    for (int j = 0; j < 4; ++j)
      *(uint4*)&op[j * 8] = *(const uint4*)&qh[px * LDQ + half * 32 + j * 8];
  }
}

// ---------------- K7: out = Wout @ gelu-out2 + bout ------------------------
// 1-D grid, XCD-grouped (r17). 2-ahead pipeline.
__global__ __launch_bounds__(256) void wout_kernel(const short* __restrict__ wh,
                                                   const short* __restrict__ out2,
                                                   const float* __restrict__ bout,
                                                   float* __restrict__ Y,
                                                   int pxbase, int NS, int nPx) {
  __shared__ short Xs[2][128 * LDX];
  const int bid = blockIdx.x;
  const int total = nPx * 64;
  const int logical = (bid & 7) * (total >> 3) + (bid >> 3);
  const int og = logical & 3;
  const int rest = logical >> 2;
  const int pxb = rest % nPx;
  const int b = rest / nPx;
  const int i0 = pxb * 128;
  const int tid = threadIdx.x, lane = tid & 63, w = tid >> 6;
  const int fr = lane & 15, fg = lane >> 4;
  const int oh = w & 1, ih = w >> 1;
  const short* W = wh + 393216 + (i64)(og * 64 + oh * 32) * 512;
  const short* Xg = out2 + ((i64)b * NS + i0) * 512;

  f32x4 acc[2][4];
  #pragma unroll
  for (int m = 0; m < 2; ++m)
    #pragma unroll
    for (int n = 0; n < 4; ++n) acc[m][n] = (f32x4)0.f;

  const int r0 = tid >> 3, scq = tid & 7;
  s16x8 sv[4];
  s16x8 Wr[2][2][2];                       // [buf][k2][m]
  auto wload = [&](int g) {
    #pragma unroll
    for (int j = 0; j < 4; ++j)
      sv[j] = *(const s16x8*)&Xg[(i64)(r0 + j * 32) * 512 + g * 64 + scq * 8];
  };
  auto wwrite = [&](int bf) {
    #pragma unroll
    for (int j = 0; j < 4; ++j) {
      const int r = r0 + j * 32;
      *(s16x8*)&Xs[bf][r * LDX + ((scq ^ ((r >> 4) & 7)) * 8)] = sv[j];
    }
  };
  auto wwload = [&](int g, int bf) {
    #pragma unroll
    for (int k2 = 0; k2 < 2; ++k2)
      #pragma unroll
      for (int m = 0; m < 2; ++m)
        Wr[bf][k2][m] = *(const s16x8*)&W[(i64)(m * 16 + fr) * 512 + g * 64 + k2 * 32 + fg * 8];
  };

  wload(0);
  wwload(0, 0);
  wwrite(0);
  wload(1);
  __syncthreads();

  #pragma unroll
  for (int ks = 0; ks < 8; ++ks) {         // BK = 64, K = 512
    if (ks < 7) wwrite((ks + 1) & 1);      // data ks+1, loaded a window ago
    if (ks < 6) wload(ks + 2);
    if (ks < 7) wwload(ks + 1, (ks + 1) & 1);
    const short* Xb = Xs[ks & 1];
    #pragma unroll
    for (int k2 = 0; k2 < 2; ++k2) {
      s16x8 bfr[4];
      #pragma unroll
      for (int n = 0; n < 4; ++n) {
        const int px = ih * 64 + n * 16 + fr;
        bfr[n] = *(const s16x8*)&Xb[px * LDX + (((k2 * 4 + fg) ^ (ih * 4 + n)) & 7) * 8];
      }
      #pragma unroll
      for (int m = 0; m < 2; ++m)
        #pragma unroll
        for (int n = 0; n < 4; ++n)
          acc[m][n] = MF(Wr[ks & 1][k2][m], bfr[n], acc[m][n]);
    }
    __syncthreads();
  }
  #pragma unroll
  for (int m = 0; m < 2; ++m)
    #pragma unroll
    for (int r = 0; r < 4; ++r) {
      const int o = og * 64 + oh * 32 + m * 16 + fg * 4 + r;
      const float bv = bout[o];
      #pragma unroll
      for (int n = 0; n < 4; ++n)
        Y[(i64)(b * 256 + o) * NPIX + pxbase + i0 + ih * 64 + n * 16 + fr] =
            acc[m][n][r] + bv;
    }
}

// ---------------------------------------------------------------------------
extern "C" void kernel_launch(void* const* d_in, const int* in_sizes, int n_in,
                              void* d_out, int out_size, void* d_ws, size_t ws_size,
                              hipStream_t stream) {
  const float* fmap = (const float*)d_in[0];
  const float* Wq   = (const float*)d_in[1];
  const float* Wdw  = (const float*)d_in[2];
  const float* Wpw  = (const float*)d_in[3];
  const float* Wout = (const float*)d_in[4];
  const float* bout = (const float*)d_in[5];
  float* out = (float*)d_out;

  char* ws = (char*)d_ws;
  short* wh     = (short*)(ws);
  float* s_part = (float*)(ws + 1048576);
  short* ctxh   = (short*)(ws + 1572864);

  const i64 HDR = 2621440;
  const int S = ((i64)ws_size - HDR >= 100663296) ? 1 : 2;
  const int NS = NPIX / S;
  const int nPx = NS / 128;

  wprep_kernel<<<2048, 256, 0, stream>>>(Wq, Wpw, Wout, wh);

  if (S == 1) {
    // layout: fmapT [2.6M, 36.2M) | dwT [36.2M, 69.7M) | ctx_part [69.7M, 86.5M)
    //         out2 aliases dwT+ctx_part: [36.2M, 103.3M)  (dead after merge)
    short* fmapT    = (short*)(ws + HDR);
    short* dwT      = (short*)(ws + 36175872);
    float* ctx_part = (float*)(ws + 69730304);   // 16.78 MB (8 slots/bh)
    short* out2     = (short*)(ws + 36175872);

    dwt_kernel<<<dim3(16, 4, 16), 256, 0, stream>>>(fmap, Wdw, dwT, fmapT);
    ctx_kernel<<<512, 512, 0, stream>>>(wh, dwT, ctx_part, s_part);
    merge_kernel<<<128, 256, 0, stream>>>(ctx_part, s_part, ctxh);
    qpv_kernel<<<nPx * 128, 256, 0, stream>>>(wh, fmapT, ctxh, out2, NS, nPx);
    wout_kernel<<<nPx * 64, 256, 0, stream>>>(wh, out2, bout, out, 0, NS, nPx);
  } else {
    // S=2 layout: ctx_part [2.6M, 19.4M) (16.78 MB) | dwT [19.4M, 52.9M)
    //             phase2: fmapT [2.6M, +16.8M) | out2 [19.4M, +33.5M)
    float* ctx_part = (float*)(ws + HDR);
    short* dwT      = (short*)(ws + 19398656);
    short* fmapT    = (short*)(ws + HDR);
    short* out2     = fmapT + (i64)16 * NS * 256;

    dwt_kernel<<<dim3(16, 4, 16), 256, 0, stream>>>(fmap, Wdw, dwT, nullptr);
    ctx_kernel<<<512, 512, 0, stream>>>(wh, dwT, ctx_part, s_part);
    merge_kernel<<<128, 256, 0, stream>>>(ctx_part, s_part, ctxh);
    for (int s = 0; s < S; ++s) {
      tcvt_kernel<<<dim3(NS / 256, 4, 16), 256, 0, stream>>>(fmap, fmapT, s * NS, NS);
      qpv_kernel<<<nPx * 128, 256, 0, stream>>>(wh, fmapT, ctxh, out2, NS, nPx);
      wout_kernel<<<nPx * 64, 256, 0, stream>>>(wh, out2, bout, out, s * NS, NS, nPx);
    }
  }
}

// Round 19
// 254.609 us; speedup vs baseline: 1.0409x; 1.0409x over previous
//
#include <hip/hip_runtime.h>
#include <math.h>

// ---------------------------------------------------------------------------
// LinearAttention: B=16, DIM=256, H=W=64 (n=4096), HEADS=8, DH=64, INNER=512
// Round 19: revert to round-16 consolidated best (254.9us measured).
// r17 XCD swizzle: timing-neutral (halved FETCH only); r18 512-thread ctx:
// regression (lockstep barriers nullify occupancy; MFMA depth halved).
// Final form: fp16 MFMA everywhere, dwt fused conv+transpose(+fmapT),
// ctx r13-form (2-ahead X pipeline, Wr dbuf, LDK=136 natural bank rotation),
// qpv load-early staging + hoisted ctxh, wout 2-ahead pipeline.
// ---------------------------------------------------------------------------

static constexpr int NPIX = 4096;
typedef long long i64;
typedef __attribute__((ext_vector_type(8))) short s16x8;
typedef __attribute__((ext_vector_type(8))) _Float16 f16x8;
typedef __attribute__((ext_vector_type(4))) float f32x4;

__device__ inline f32x4 MF(s16x8 a, s16x8 b, f32x4 c) {
  return __builtin_amdgcn_mfma_f32_16x16x32_f16(
      __builtin_bit_cast(f16x8, a), __builtin_bit_cast(f16x8, b), c, 0, 0, 0);
}
__device__ inline short f2h(float x) {
  return __builtin_bit_cast(short, (_Float16)x);
}
__device__ inline unsigned pk2(float a, float b) {
  return (unsigned)(unsigned short)f2h(a) | ((unsigned)(unsigned short)f2h(b) << 16);
}

#define LDX 72    // Xs row stride in shorts (64 c + 8 pad, 144B)
#define LDK 136   // kh/vv row stride in shorts (128 px + 8 pad; 17 groups ≡ 1 mod 8)
#define LDQ 72    // qh row stride in shorts (64 + 8 pad, 144B)

// ---------------- K1: depthwise 3x3 + transpose; optional fmapT pass -------
__global__ __launch_bounds__(256) void dwt_kernel(const float* __restrict__ fmap,
                                                  const float* __restrict__ Wdw,
                                                  short* __restrict__ dwT,
                                                  short* __restrict__ fmapT) {
  __shared__ short T[64 * 260];
  const int pxt = blockIdx.x * 256, ct = blockIdx.y * 64, b = blockIdx.z;
  const int t = threadIdx.x;
  const int x0 = pxt >> 6;
  const int yq = t & 15, xq = (t >> 4) & 3, clo = t >> 6;
  const int y0 = yq * 4;
  const int x = x0 + xq;
  #pragma unroll 2
  for (int cc = 0; cc < 16; ++cc) {
    const int cl = cc * 4 + clo;
    const int cg = ct + cl;
    const float* img = fmap + (i64)(b * 256 + cg) * NPIX;
    const float* w = Wdw + cg * 9;
    float a0 = 0.f, a1 = 0.f, a2 = 0.f, a3 = 0.f;
    #pragma unroll
    for (int dx = -1; dx <= 1; ++dx) {
      const int xx = x + dx;
      if ((unsigned)xx < 64u) {
        const float* row = img + xx * 64 + y0;
        const f32x4 v = *(const f32x4*)row;
        const float vm = (y0 > 0)  ? row[-1] : 0.f;
        const float vp = (y0 < 60) ? row[4]  : 0.f;
        const float wm = w[(dx + 1) * 3], wc = w[(dx + 1) * 3 + 1], wp = w[(dx + 1) * 3 + 2];
        a0 = fmaf(wm, vm,   fmaf(wc, v[0], fmaf(wp, v[1], a0)));
        a1 = fmaf(wm, v[0], fmaf(wc, v[1], fmaf(wp, v[2], a1)));
        a2 = fmaf(wm, v[1], fmaf(wc, v[2], fmaf(wp, v[3], a2)));
        a3 = fmaf(wm, v[2], fmaf(wc, v[3], fmaf(wp, vp,   a3)));
      }
    }
    *(uint2*)&T[cl * 260 + xq * 64 + y0] = make_uint2(pk2(a0, a1), pk2(a2, a3));
  }
  __syncthreads();
  {
    short arr[64];
    #pragma unroll
    for (int c = 0; c < 64; ++c) arr[c] = T[c * 260 + t];
    short* dp = dwT + ((i64)b * NPIX + pxt + t) * 256 + ct;
    #pragma unroll
    for (int j = 0; j < 8; ++j)
      *(uint4*)&dp[j * 8] = *(const uint4*)&arr[j * 8];
  }
  if (fmapT) {
    __syncthreads();
    #pragma unroll 4
    for (int cc = 0; cc < 16; ++cc) {
      const int cl = cc * 4 + clo;
      const float* img = fmap + (i64)(b * 256 + ct + cl) * NPIX;
      const f32x4 vc = *(const f32x4*)(img + x * 64 + y0);
      *(uint2*)&T[cl * 260 + xq * 64 + y0] = make_uint2(pk2(vc[0], vc[1]), pk2(vc[2], vc[3]));
    }
    __syncthreads();
    short arr[64];
    #pragma unroll
    for (int c = 0; c < 64; ++c) arr[c] = T[c * 260 + t];
    short* fp = fmapT + ((i64)b * NPIX + pxt + t) * 256 + ct;
    #pragma unroll
    for (int j = 0; j < 8; ++j)
      *(uint4*)&fp[j * 8] = *(const uint4*)&arr[j * 8];
  }
}

// ---------------- K2: weights -> fp16 --------------------------------------
__global__ __launch_bounds__(256) void wprep_kernel(const float* __restrict__ Wq,
                                                    const float* __restrict__ Wpw,
                                                    const float* __restrict__ Wout,
                                                    short* __restrict__ wh) {
  int i = blockIdx.x * 256 + threadIdx.x;
  float v;
  if (i < 131072) v = Wq[i];
  else if (i < 393216) v = Wpw[i - 131072];
  else v = Wout[i - 393216];
  wh[i] = f2h(v);
}

// ---------------- K3: transpose+convert fp32 [c][px] -> fp16 [px][c] -------
// (S=2 fallback path only)
__global__ __launch_bounds__(256) void tcvt_kernel(const float* __restrict__ src,
                                                   short* __restrict__ dst,
                                                   int src_px0, int nsl) {
  __shared__ short T[64 * 260];
  const int pxt = blockIdx.x * 256, ct = blockIdx.y * 64, b = blockIdx.z;
  const int t = threadIdx.x;
  const int pxq = t & 63, cl = t >> 6;
  const float* sp = src + (i64)(b * 256 + ct) * NPIX + src_px0 + pxt;
  #pragma unroll
  for (int cc = 0; cc < 16; ++cc) {
    const int c = cl + cc * 4;
    f32x4 v = *(const f32x4*)&sp[(i64)c * NPIX + pxq * 4];
    *(uint2*)&T[c * 260 + pxq * 4] = make_uint2(pk2(v[0], v[1]), pk2(v[2], v[3]));
  }
  __syncthreads();
  short arr[64];
  #pragma unroll
  for (int c = 0; c < 64; ++c) arr[c] = T[c * 260 + t];
  short* dp = dst + ((i64)b * nsl + pxt + t) * 256 + ct;
  #pragma unroll
  for (int j = 0; j < 8; ++j)
    *(uint4*)&dp[j * 8] = *(const uint4*)&arr[j * 8];
}

// ---------------- K4: fused k/v GEMM + exp + ctx partial -------------------
// grid (4 chunks of 1024 px, 8 h, 16 b). ROUND-13 FORM (76.1us measured):
// 2-window-ahead X pipeline, Wr register double-buffer, full-width kh/vv
// (LDK=136, natural bank rotation), single-phase GEMM2, no bottom barrier.
__global__ __launch_bounds__(256) void ctx_kernel(const short* __restrict__ wh,
                                                  const short* __restrict__ dwT,
                                                  float* __restrict__ ctx_part,
                                                  float* __restrict__ s_part) {
  __shared__ short Xs[2][128 * LDX];
  __shared__ short kh[64 * LDK];
  __shared__ short vv[64 * LDK];
  const int chunk = blockIdx.x, h = blockIdx.y, b = blockIdx.z;
  const int tid = threadIdx.x, lane = tid & 63, w = tid >> 6;
  const int fr = lane & 15, fg = lane >> 4;
  const int wcv = w & 1, wpx = w >> 1;     // wcv: k/v half; wpx: px half
  const int wrow0 = (wcv ? 512 : 0) + h * 64;
  const short* W = wh + 131072 + (i64)wrow0 * 256;
  const short* Xg = dwT + ((i64)b * NPIX + chunk * 1024) * 256;

  f32x4 acc2[2][2];
  #pragma unroll
  for (int m = 0; m < 2; ++m)
    #pragma unroll
    for (int n = 0; n < 2; ++n) acc2[m][n] = (f32x4)0.f;
  float srun[4] = {0.f, 0.f, 0.f, 0.f};

  const int r0 = tid >> 3, scq = tid & 7;  // staging: 32 rows x 8 col-groups
  s16x8 sv[4];
  s16x8 Wr[2][2][4];                       // [buf][k2][n]
  auto cload = [&](int g) {
    const int itg = g >> 2, c0g = (g & 3) * 64;
    #pragma unroll
    for (int j = 0; j < 4; ++j)
      sv[j] = *(const s16x8*)&Xg[(i64)(itg * 128 + r0 + j * 32) * 256 + c0g + scq * 8];
  };
  auto cwrite = [&](int bf) {
    #pragma unroll
    for (int j = 0; j < 4; ++j) {
      const int r = r0 + j * 32;
      *(s16x8*)&Xs[bf][r * LDX + ((scq ^ ((r >> 4) & 7)) * 8)] = sv[j];
    }
  };
  auto wload = [&](int g, int bf) {
    const int c0g = (g & 3) * 64;
    #pragma unroll
    for (int k2 = 0; k2 < 2; ++k2)
      #pragma unroll
      for (int n = 0; n < 4; ++n)
        Wr[bf][k2][n] = *(const s16x8*)&W[(i64)(n * 16 + fr) * 256 + c0g + k2 * 32 + fg * 8];
  };

  // prologue: Xs[0] <- data0; sv <- data1; Wr[0] <- W0
  cload(0);
  wload(0, 0);
  cwrite(0);
  cload(1);
  __syncthreads();

  for (int it = 0; it < 8; ++it) {
    f32x4 acc1[4][4];
    #pragma unroll
    for (int m = 0; m < 4; ++m)
      #pragma unroll
      for (int n = 0; n < 4; ++n) acc1[m][n] = (f32x4)0.f;

    #pragma unroll
    for (int ks = 0; ks < 4; ++ks) {
      const int g = it * 4 + ks;           // g&1 == ks&1 (it*4 even)
      if (g < 31) cwrite((ks + 1) & 1);    // data loaded a full window ago
      if (g < 30) cload(g + 2);            // refill sv, 2 windows ahead
      if (g < 31) wload(g + 1, (ks + 1) & 1);
      const short* Xb = Xs[ks & 1];
      #pragma unroll
      for (int k2 = 0; k2 < 2; ++k2) {
        s16x8 a[4];
        #pragma unroll
        for (int m = 0; m < 4; ++m) {
          const int px = wpx * 64 + m * 16 + fr;
          a[m] = *(const s16x8*)&Xb[px * LDX + (((k2 * 4 + fg) ^ (wpx * 4 + m)) & 7) * 8];
        }
        #pragma unroll
        for (int m = 0; m < 4; ++m)
          #pragma unroll
          for (int n = 0; n < 4; ++n)
            acc1[m][n] = MF(a[m], Wr[ks & 1][k2][n], acc1[m][n]);
      }
      __syncthreads();
    }
    // k-half: exp (no max-sub; values bounded), per-channel running sums
    if (wcv == 0) {
      #pragma unroll
      for (int m = 0; m < 4; ++m)
        #pragma unroll
        for (int n = 0; n < 4; ++n)
          #pragma unroll
          for (int r = 0; r < 4; ++r) {
            float e = __expf(acc1[m][n][r]);
            acc1[m][n][r] = e;
            srun[n] += e;
          }
    }
    // packed writes into [ch][px]; NO XOR (LDK stride rotates banks)
    {
      short* dst = wcv ? vv : kh;
      #pragma unroll
      for (int m = 0; m < 4; ++m)
        #pragma unroll
        for (int n = 0; n < 4; ++n) {
          const int ch = n * 16 + fr;
          const int col = (wpx * 8 + m * 2 + (fg >> 1)) * 8 + (fg & 1) * 4;
          *(uint2*)&dst[ch * LDK + col] =
              make_uint2(pk2(acc1[m][n][0], acc1[m][n][1]),
                         pk2(acc1[m][n][2], acc1[m][n][3]));
        }
    }
    __syncthreads();
    // GEMM2: ctx[d][e] += sum_px kh[d][px] * vv[e][px]
    #pragma unroll
    for (int k2 = 0; k2 < 4; ++k2) {
      const int colg = (k2 * 4 + fg) * 8;
      s16x8 a2[2], b2[2];
      #pragma unroll
      for (int m2 = 0; m2 < 2; ++m2)
        a2[m2] = *(const s16x8*)&kh[(wcv * 32 + m2 * 16 + fr) * LDK + colg];
      #pragma unroll
      for (int n2 = 0; n2 < 2; ++n2)
        b2[n2] = *(const s16x8*)&vv[(wpx * 32 + n2 * 16 + fr) * LDK + colg];
      #pragma unroll
      for (int m2 = 0; m2 < 2; ++m2)
        #pragma unroll
        for (int n2 = 0; n2 < 2; ++n2)
          acc2[m2][n2] = MF(a2[m2], b2[n2], acc2[m2][n2]);
    }
    // no bottom barrier: next it's window barriers separate GEMM2 reads
    // from the next kh/vv writes.
  }
  __syncthreads();   // last GEMM2 reads done before kh reuse as sredp
  // write ctx partial [d][e]
  float* cp = ctx_part + (i64)((b * 8 + h) * 4 + chunk) * 4096;
  #pragma unroll
  for (int m2 = 0; m2 < 2; ++m2)
    #pragma unroll
    for (int n2 = 0; n2 < 2; ++n2)
      #pragma unroll
      for (int r = 0; r < 4; ++r) {
        const int d = wcv * 32 + m2 * 16 + fg * 4 + r;
        const int e = wpx * 32 + n2 * 16 + fr;
        cp[d * 64 + e] = acc2[m2][n2][r];
      }
  // per-channel sumexp: reduce over fg lanes, stash in kh (dead), emit
  float* sredp = (float*)kh;
  if (wcv == 0) {
    #pragma unroll
    for (int n = 0; n < 4; ++n) {
      float s = srun[n];
      s += __shfl_xor(s, 16);
      s += __shfl_xor(s, 32);
      if (fg == 0) sredp[wpx * 64 + n * 16 + fr] = s;
    }
  }
  __syncthreads();
  if (tid < 64)
    s_part[(i64)((b * 8 + h) * 4 + chunk) * 64 + tid] = sredp[tid] + sredp[64 + tid];
}

// ---------------- K5: merge chunk partials -> ctxh fp16 [bh][e][d] ---------
__global__ __launch_bounds__(256) void merge_kernel(const float* __restrict__ part,
                                                    const float* __restrict__ s_part,
                                                    short* __restrict__ ctxh) {
  const int bh = blockIdx.x, t = threadIdx.x;
  const int e = t & 63, db = t >> 6;
  const float* p = part + (i64)bh * 4 * 4096;
  const float* sp = s_part + (i64)bh * 4 * 64;
  #pragma unroll 4
  for (int dd = 0; dd < 16; ++dd) {
    const int d = db * 16 + dd;
    float s = 0.f, c = 0.f;
    #pragma unroll
    for (int k = 0; k < 4; ++k) {
      s += sp[k * 64 + d];
      c += p[k * 4096 + d * 64 + e];
    }
    ctxh[(i64)bh * 4096 + e * 64 + d] = f2h(c / s);
  }
}

// ---------------- K6: fused q GEMM + softmax + PV + GELU -> out2 -----------
// grid (NS/128, 8 h, 16 b). Load-early staging + W reg dbuf + hoisted ctxh.
__global__ __launch_bounds__(256) void qpv_kernel(const short* __restrict__ wh,
                                                  const short* __restrict__ fmapT,
                                                  const short* __restrict__ ctxh,
                                                  short* __restrict__ out2, int NS) {
  __shared__ short Xs[128 * LDX];
  __shared__ short qh[128 * LDQ];
  __shared__ float sden[2][128];
  const int h = blockIdx.y, b = blockIdx.z;
  const int i0 = blockIdx.x * 128;
  const int tid = threadIdx.x, lane = tid & 63, w = tid >> 6;
  const int fr = lane & 15, fg = lane >> 4;
  const int dh = w & 1, ih = w >> 1;
  const short* W = wh + (i64)(h * 64 + dh * 32) * 256;
  const short* Xg = fmapT + ((i64)b * NS + i0) * 256;

  // hoist PV A-operand (ctxh, 1MB L2-resident): fully hidden under q-GEMM
  const i64 cbase = (i64)(b * 8 + h) * 4096;
  s16x8 ca[2][2];                          // [k2][m2]
  #pragma unroll
  for (int k2 = 0; k2 < 2; ++k2)
    #pragma unroll
    for (int m2 = 0; m2 < 2; ++m2)
      ca[k2][m2] = *(const s16x8*)&ctxh[cbase + (i64)(dh * 32 + m2 * 16 + fr) * 64 + k2 * 32 + fg * 8];

  f32x4 acc[2][4];
  #pragma unroll
  for (int m = 0; m < 2; ++m)
    #pragma unroll
    for (int n = 0; n < 4; ++n) acc[m][n] = (f32x4)0.f;

  const int r0 = tid >> 3, scq = tid & 7;
  s16x8 sv[4];
  s16x8 Wr[2][2][2];                       // [buf][k2][m]
  auto qload = [&](int g) {
    #pragma unroll
    for (int j = 0; j < 4; ++j)
      sv[j] = *(const s16x8*)&Xg[(i64)(r0 + j * 32) * 256 + g * 64 + scq * 8];
  };
  auto qwrite = [&]() {
    #pragma unroll
    for (int j = 0; j < 4; ++j) {
      const int r = r0 + j * 32;
      *(s16x8*)&Xs[r * LDX + ((scq ^ ((r >> 4) & 7)) * 8)] = sv[j];
    }
  };
  auto wqload = [&](int g, int bf) {
    #pragma unroll
    for (int k2 = 0; k2 < 2; ++k2)
      #pragma unroll
      for (int m = 0; m < 2; ++m)
        Wr[bf][k2][m] = *(const s16x8*)&W[(i64)(m * 16 + fr) * 256 + g * 64 + k2 * 32 + fg * 8];
  };

  qload(0);
  wqload(0, 0);

  for (int ks = 0; ks < 4; ++ks) {         // BK = 64
    qwrite();                              // drains vmcnt for window-ks loads
    if (ks < 3) {
      qload(ks + 1);                       // issue next window: full-window margin
      wqload(ks + 1, (ks + 1) & 1);
    }
    __syncthreads();
    #pragma unroll
    for (int k2 = 0; k2 < 2; ++k2) {
      s16x8 bfr[4];
      #pragma unroll
      for (int n = 0; n < 4; ++n) {
        const int px = ih * 64 + n * 16 + fr;
        bfr[n] = *(const s16x8*)&Xs[px * LDX + (((k2 * 4 + fg) ^ (ih * 4 + n)) & 7) * 8];
      }
      #pragma unroll
      for (int m = 0; m < 2; ++m)
        #pragma unroll
        for (int n = 0; n < 4; ++n)
          acc[m][n] = MF(Wr[ks & 1][k2][m], bfr[n], acc[m][n]);
    }
    __syncthreads();                       // Xs reads done before next qwrite
  }
  // exp + per-pixel denominator across d (2 waves x 32 d)
  #pragma unroll
  for (int n = 0; n < 4; ++n) {
    float s = 0.f;
    #pragma unroll
    for (int m = 0; m < 2; ++m)
      #pragma unroll
      for (int r = 0; r < 4; ++r) {
        float e = __expf(acc[m][n][r]);
        acc[m][n][r] = e;
        s += e;
      }
    s += __shfl_xor(s, 16);
    s += __shfl_xor(s, 32);
    if (fg == 0) sden[dh][ih * 64 + n * 16 + fr] = s;
  }
  __syncthreads();
  if (tid < 128) sden[0][tid] += sden[1][tid];
  __syncthreads();
  // qhat -> LDS [px][d] fp16 (uint2-packed 4-d chunks)
  #pragma unroll
  for (int n = 0; n < 4; ++n) {
    const int il = ih * 64 + n * 16 + fr;
    const float rs = 0.125f / sden[0][il];
    #pragma unroll
    for (int m = 0; m < 2; ++m) {
      const int d0 = dh * 32 + m * 16 + fg * 4;
      *(uint2*)&qh[il * LDQ + d0] =
          make_uint2(pk2(acc[m][n][0] * rs, acc[m][n][1] * rs),
                     pk2(acc[m][n][2] * rs, acc[m][n][3] * rs));
    }
  }
  __syncthreads();
  // PV: out2[e][px] = sum_d ctx[e][d] * qhat[px][d]  (A = hoisted ca)
  f32x4 acc3[2][4];
  #pragma unroll
  for (int m = 0; m < 2; ++m)
    #pragma unroll
    for (int n = 0; n < 4; ++n) acc3[m][n] = (f32x4)0.f;
  #pragma unroll
  for (int k2 = 0; k2 < 2; ++k2) {
    s16x8 b2[4];
    #pragma unroll
    for (int n2 = 0; n2 < 4; ++n2)
      b2[n2] = *(const s16x8*)&qh[(ih * 64 + n2 * 16 + fr) * LDQ + k2 * 32 + fg * 8];
    #pragma unroll
    for (int m2 = 0; m2 < 2; ++m2)
      #pragma unroll
      for (int n2 = 0; n2 < 4; ++n2)
        acc3[m2][n2] = MF(ca[k2][m2], b2[n2], acc3[m2][n2]);
  }
  __syncthreads();   // qh reads done; reuse as transpose buffer
  // GELU + fp16, into qh as [px][e]
  #pragma unroll
  for (int m2 = 0; m2 < 2; ++m2)
    #pragma unroll
    for (int n2 = 0; n2 < 4; ++n2) {
      const int px = ih * 64 + n2 * 16 + fr;
      const int e0 = dh * 32 + m2 * 16 + fg * 4;
      float g[4];
      #pragma unroll
      for (int r = 0; r < 4; ++r) {
        float v = acc3[m2][n2][r];
        g[r] = 0.5f * v * (1.0f + erff(v * 0.70710678118654752f));
      }
      *(uint2*)&qh[px * LDQ + e0] = make_uint2(pk2(g[0], g[1]), pk2(g[2], g[3]));
    }
  __syncthreads();
  // coalesced out2 store: [b][px][512ch]
  {
    const int px = tid >> 1, half = tid & 1;
    short* op = out2 + ((i64)b * NS + i0 + px) * 512 + h * 64 + half * 32;
    #pragma unroll
    for (int j = 0; j < 4; ++j)
      *(uint4*)&op[j * 8] = *(const uint4*)&qh[px * LDQ + half * 32 + j * 8];
  }
}

// ---------------- K7: out = Wout @ gelu-out2 + bout ------------------------
// grid (NS/128, 4 og, 16 b). M=64 o x N=128 px, K=512. 2-ahead pipeline.
__global__ __launch_bounds__(256) void wout_kernel(const short* __restrict__ wh,
                                                   const short* __restrict__ out2,
                                                   const float* __restrict__ bout,
                                                   float* __restrict__ Y,
                                                   int pxbase, int NS) {
  __shared__ short Xs[2][128 * LDX];
  const int og = blockIdx.y, b = blockIdx.z;
  const int i0 = blockIdx.x * 128;
  const int tid = threadIdx.x, lane = tid & 63, w = tid >> 6;
  const int fr = lane & 15, fg = lane >> 4;
  const int oh = w & 1, ih = w >> 1;
  const short* W = wh + 393216 + (i64)(og * 64 + oh * 32) * 512;
  const short* Xg = out2 + ((i64)b * NS + i0) * 512;

  f32x4 acc[2][4];
  #pragma unroll
  for (int m = 0; m < 2; ++m)
    #pragma unroll
    for (int n = 0; n < 4; ++n) acc[m][n] = (f32x4)0.f;

  const int r0 = tid >> 3, scq = tid & 7;
  s16x8 sv[4];
  s16x8 Wr[2][2][2];                       // [buf][k2][m]
  auto wload = [&](int g) {
    #pragma unroll
    for (int j = 0; j < 4; ++j)
      sv[j] = *(const s16x8*)&Xg[(i64)(r0 + j * 32) * 512 + g * 64 + scq * 8];
  };
  auto wwrite = [&](int bf) {
    #pragma unroll
    for (int j = 0; j < 4; ++j) {
      const int r = r0 + j * 32;
      *(s16x8*)&Xs[bf][r * LDX + ((scq ^ ((r >> 4) & 7)) * 8)] = sv[j];
    }
  };
  auto wwload = [&](int g, int bf) {
    #pragma unroll
    for (int k2 = 0; k2 < 2; ++k2)
      #pragma unroll
      for (int m = 0; m < 2; ++m)
        Wr[bf][k2][m] = *(const s16x8*)&W[(i64)(m * 16 + fr) * 512 + g * 64 + k2 * 32 + fg * 8];
  };

  wload(0);
  wwload(0, 0);
  wwrite(0);
  wload(1);
  __syncthreads();

  #pragma unroll
  for (int ks = 0; ks < 8; ++ks) {         // BK = 64, K = 512
    if (ks < 7) wwrite((ks + 1) & 1);      // data ks+1, loaded a window ago
    if (ks < 6) wload(ks + 2);
    if (ks < 7) wwload(ks + 1, (ks + 1) & 1);
    const short* Xb = Xs[ks & 1];
    #pragma unroll
    for (int k2 = 0; k2 < 2; ++k2) {
      s16x8 bfr[4];
      #pragma unroll
      for (int n = 0; n < 4; ++n) {
        const int px = ih * 64 + n * 16 + fr;
        bfr[n] = *(const s16x8*)&Xb[px * LDX + (((k2 * 4 + fg) ^ (ih * 4 + n)) & 7) * 8];
      }
      #pragma unroll
      for (int m = 0; m < 2; ++m)
        #pragma unroll
        for (int n = 0; n < 4; ++n)
          acc[m][n] = MF(Wr[ks & 1][k2][m], bfr[n], acc[m][n]);
    }
    __syncthreads();
  }
  #pragma unroll
  for (int m = 0; m < 2; ++m)
    #pragma unroll
    for (int r = 0; r < 4; ++r) {
      const int o = og * 64 + oh * 32 + m * 16 + fg * 4 + r;
      const float bv = bout[o];
      #pragma unroll
      for (int n = 0; n < 4; ++n)
        Y[(i64)(b * 256 + o) * NPIX + pxbase + i0 + ih * 64 + n * 16 + fr] =
            acc[m][n][r] + bv;
    }
}

// ---------------------------------------------------------------------------
extern "C" void kernel_launch(void* const* d_in, const int* in_sizes, int n_in,
                              void* d_out, int out_size, void* d_ws, size_t ws_size,
                              hipStream_t stream) {
  const float* fmap = (const float*)d_in[0];
  const float* Wq   = (const float*)d_in[1];
  const float* Wdw  = (const float*)d_in[2];
  const float* Wpw  = (const float*)d_in[3];
  const float* Wout = (const float*)d_in[4];
  const float* bout = (const float*)d_in[5];
  float* out = (float*)d_out;

  char* ws = (char*)d_ws;
  short* wh     = (short*)(ws);
  float* s_part = (float*)(ws + 1048576);
  short* ctxh   = (short*)(ws + 1572864);

  const i64 HDR = 2621440;
  const int S = ((i64)ws_size - HDR >= 100663296) ? 1 : 2;
  const int NS = NPIX / S;

  wprep_kernel<<<2048, 256, 0, stream>>>(Wq, Wpw, Wout, wh);

  if (S == 1) {
    // layout: fmapT [2.6M, 36.2M) | dwT [36.2M, 69.7M) | ctx_part [69.7M, 78.1M)
    //         out2 aliases dwT+ctx_part: [36.2M, 103.3M)  (dead after merge)
    short* fmapT    = (short*)(ws + HDR);
    short* dwT      = (short*)(ws + 36175872);
    float* ctx_part = (float*)(ws + 69730304);
    short* out2     = (short*)(ws + 36175872);

    dwt_kernel<<<dim3(16, 4, 16), 256, 0, stream>>>(fmap, Wdw, dwT, fmapT);
    ctx_kernel<<<dim3(4, 8, 16), 256, 0, stream>>>(wh, dwT, ctx_part, s_part);
    merge_kernel<<<128, 256, 0, stream>>>(ctx_part, s_part, ctxh);
    qpv_kernel<<<dim3(NS / 128, 8, 16), 256, 0, stream>>>(wh, fmapT, ctxh, out2, NS);
    wout_kernel<<<dim3(NS / 128, 4, 16), 256, 0, stream>>>(wh, out2, bout, out, 0, NS);
  } else {
    // S=2 layout: ctx_part [2.6M, 19.4M) | dwT [19.4M, 52.9M)
    //             phase2: fmapT [2.6M, +16.8M) | out2 [19.4M, +33.5M)
    float* ctx_part = (float*)(ws + HDR);
    short* dwT      = (short*)(ws + 19398656);
    short* fmapT    = (short*)(ws + HDR);
    short* out2     = fmapT + (i64)16 * NS * 256;

    dwt_kernel<<<dim3(16, 4, 16), 256, 0, stream>>>(fmap, Wdw, dwT, nullptr);
    ctx_kernel<<<dim3(4, 8, 16), 256, 0, stream>>>(wh, dwT, ctx_part, s_part);
    merge_kernel<<<128, 256, 0, stream>>>(ctx_part, s_part, ctxh);
    for (int s = 0; s < S; ++s) {
      tcvt_kernel<<<dim3(NS / 256, 4, 16), 256, 0, stream>>>(fmap, fmapT, s * NS, NS);
      qpv_kernel<<<dim3(NS / 128, 8, 16), 256, 0, stream>>>(wh, fmapT, ctxh, out2, NS);
      wout_kernel<<<dim3(NS / 128, 4, 16), 256, 0, stream>>>(wh, out2, bout, out, s * NS, NS);
    }
  }
}